// Round 3
// baseline (226.716 us; speedup 1.0000x reference)
//
#include <hip/hip_runtime.h>
#include <math.h>

#define N_BINS 15
#define NSLOTS (3 * N_BINS)   // 45: [count | sum_conf | sum_acc] x 15 bins
#define NBLOCKS 2048

// One wave (64 lanes) per row, grid-stride over rows. C=1000 floats = 250
// float4; each lane holds 4 float4 in registers so max-pass and sum-exp pass
// read HBM exactly once. Per-block bin sums land in LDS, then are written
// NON-atomically to partial[slot][block] (no 92K-atomic tail, no memset).
__global__ __launch_bounds__(256) void ece_main(const float* __restrict__ logits,
                                                const int* __restrict__ labels,
                                                float* __restrict__ partial, // [NSLOTS][NBLOCKS] or gbins[45] (atomic fallback)
                                                int N, int C, int useAtomic) {
    __shared__ float sb[NSLOTS];
    const int tid = threadIdx.x;
    if (tid < NSLOTS) sb[tid] = 0.0f;
    __syncthreads();

    const int lane = tid & 63;
    const int wid  = tid >> 6;
    const int wavesPerBlock = blockDim.x >> 6;
    const int wavesTotal = gridDim.x * wavesPerBlock;
    const int C4 = C >> 2;  // 250 for C=1000

    for (int row = blockIdx.x * wavesPerBlock + wid; row < N; row += wavesTotal) {
        int lbl = labels[row];
        const float4* rp = (const float4*)(logits + (size_t)row * C);
        float4 v[4];
        #pragma unroll
        for (int c = 0; c < 4; ++c) {
            int f4i = c * 64 + lane;
            v[c] = (f4i < C4) ? rp[f4i]
                              : make_float4(-INFINITY, -INFINITY, -INFINITY, -INFINITY);
        }

        // per-lane max + first-occurrence argmax (ascending scan, strict >)
        float m = -INFINITY;
        int   mi = 0x7fffffff;
        #pragma unroll
        for (int c = 0; c < 4; ++c) {
            const float* e = (const float*)&v[c];
            int base = (c * 64 + lane) * 4;
            #pragma unroll
            for (int j = 0; j < 4; ++j) {
                if (e[j] > m) { m = e[j]; mi = base + j; }
            }
        }
        // wave reduce: max, tie-break to smallest index
        #pragma unroll
        for (int off = 1; off < 64; off <<= 1) {
            float om = __shfl_xor(m, off, 64);
            int   oi = __shfl_xor(mi, off, 64);
            if (om > m || (om == m && oi < mi)) { m = om; mi = oi; }
        }

        // sum of exp(x - max); -inf fill lanes contribute exp(-inf)=0
        float s = 0.0f;
        #pragma unroll
        for (int c = 0; c < 4; ++c) {
            const float* e = (const float*)&v[c];
            #pragma unroll
            for (int j = 0; j < 4; ++j) s += __expf(e[j] - m);
        }
        #pragma unroll
        for (int off = 1; off < 64; off <<= 1) s += __shfl_xor(s, off, 64);

        if (lane == 0) {
            float conf = 1.0f / s;                        // exp(max-max)/Z = 1/Z
            int bin = (int)ceilf(conf * (float)N_BINS) - 1;
            bin = bin < 0 ? 0 : (bin > N_BINS - 1 ? N_BINS - 1 : bin);
            float acc = (mi == lbl) ? 1.0f : 0.0f;
            atomicAdd(&sb[bin], 1.0f);
            atomicAdd(&sb[N_BINS + bin], conf);
            atomicAdd(&sb[2 * N_BINS + bin], acc);
        }
    }
    __syncthreads();
    if (tid < NSLOTS) {
        if (useAtomic) atomicAdd(&partial[tid], sb[tid]);
        else           partial[(size_t)tid * gridDim.x + blockIdx.x] = sb[tid];
    }
}

// Single block, 16 waves. Each wave tree-reduces 3 slots (2048 partials each,
// coalesced), then threads 0..14 compute the 31 outputs:
// [ece, confs_binned[15], accs_binned[15]]
__global__ __launch_bounds__(1024) void ece_final(const float* __restrict__ partial,
                                                  float* __restrict__ out,
                                                  float invN, int nparts, int useAtomic) {
    __shared__ float red[NSLOTS];
    __shared__ float s_ece[N_BINS];
    const int tid = threadIdx.x;
    const int lane = tid & 63;
    const int w    = tid >> 6;   // 16 waves

    if (useAtomic) {
        if (tid < NSLOTS) red[tid] = partial[tid];
    } else {
        for (int slot = w; slot < NSLOTS; slot += 16) {
            const float* p = partial + (size_t)slot * nparts;
            float a = 0.0f;
            for (int i = lane; i < nparts; i += 64) a += p[i];
            #pragma unroll
            for (int off = 1; off < 64; off <<= 1) a += __shfl_xor(a, off, 64);
            if (lane == 0) red[slot] = a;
        }
    }
    __syncthreads();

    if (tid < N_BINS) {
        float cnt   = red[tid];
        float sconf = red[N_BINS + tid];
        float sacc  = red[2 * N_BINS + tid];
        bool  ne    = cnt > 0.0f;
        float sc    = ne ? cnt : 1.0f;
        float avg_conf = sconf / sc;
        float avg_acc  = sacc / sc;
        float prop     = cnt * invN;
        s_ece[tid] = ne ? fabsf(avg_conf - avg_acc) * prop : 0.0f;
        out[1 + tid]          = ne ? avg_conf : ((float)tid + 0.5f) / (float)N_BINS;
        out[1 + N_BINS + tid] = ne ? avg_acc  : 0.0f;
    }
    __syncthreads();
    if (tid == 0) {
        float e = 0.0f;
        for (int j = 0; j < N_BINS; ++j) e += s_ece[j];
        out[0] = e;
    }
}

extern "C" void kernel_launch(void* const* d_in, const int* in_sizes, int n_in,
                              void* d_out, int out_size, void* d_ws, size_t ws_size,
                              hipStream_t stream) {
    const float* logits = (const float*)d_in[0];
    const int*   labels = (const int*)d_in[1];
    int N = in_sizes[1];
    int C = in_sizes[0] / N;   // 1000

    float* ws = (float*)d_ws;
    size_t needed = (size_t)NSLOTS * NBLOCKS * sizeof(float);
    int useAtomic = (ws_size < needed) ? 1 : 0;

    if (useAtomic) {
        hipMemsetAsync(ws, 0, NSLOTS * sizeof(float), stream);
    }
    ece_main<<<NBLOCKS, 256, 0, stream>>>(logits, labels, ws, N, C, useAtomic);
    ece_final<<<1, 1024, 0, stream>>>(ws, (float*)d_out, 1.0f / (float)N,
                                      NBLOCKS, useAtomic);
}

// Round 5
// 189.727 us; speedup vs baseline: 1.1950x; 1.1950x over previous
//
#include <hip/hip_runtime.h>
#include <math.h>

#define N_BINS 15

typedef float fvec4 __attribute__((ext_vector_type(4)));  // native clang vector:
// __builtin_nontemporal_load needs scalar/native-vector, not HIP_vector_type.

// One wave (64 lanes) per row, grid-stride over rows, software-prefetched,
// NONTEMPORAL logits loads (pure 1.05 GB stream, zero reuse -> don't retain
// in L2/L3). Per-block bin sums in LDS; 45 global atomics per block at end
// (measured faster than the two-stage partial-write scheme, R3).
__global__ __launch_bounds__(256) void ece_main(const float* __restrict__ logits,
                                                const int* __restrict__ labels,
                                                float* __restrict__ gbins, // [3][N_BINS]
                                                int N, int C) {
    __shared__ float sb[3 * N_BINS];
    const int tid = threadIdx.x;
    if (tid < 3 * N_BINS) sb[tid] = 0.0f;
    __syncthreads();

    const int lane = tid & 63;
    const int wid  = tid >> 6;
    const int wavesPerBlock = blockDim.x >> 6;
    const int wavesTotal = gridDim.x * wavesPerBlock;
    const int C4 = C >> 2;  // 250 for C=1000

    int row = blockIdx.x * wavesPerBlock + wid;

    fvec4 v[4];
    const fvec4 ninf = (fvec4)(-INFINITY);
    if (row < N) {
        const fvec4* rp = (const fvec4*)(logits + (size_t)row * C);
        #pragma unroll
        for (int c = 0; c < 4; ++c) {
            int f4i = c * 64 + lane;
            v[c] = (f4i < C4) ? __builtin_nontemporal_load(&rp[f4i]) : ninf;
        }
    }

    for (; row < N; row += wavesTotal) {
        int lbl = labels[row];

        // prefetch next row while we reduce this one
        int nrow = row + wavesTotal;
        fvec4 vn[4];
        if (nrow < N) {
            const fvec4* np = (const fvec4*)(logits + (size_t)nrow * C);
            #pragma unroll
            for (int c = 0; c < 4; ++c) {
                int f4i = c * 64 + lane;
                vn[c] = (f4i < C4) ? __builtin_nontemporal_load(&np[f4i]) : ninf;
            }
        } else {
            #pragma unroll
            for (int c = 0; c < 4; ++c) vn[c] = ninf;
        }

        // per-lane max + first-occurrence argmax (ascending scan, strict >)
        float m = -INFINITY;
        int   mi = 0x7fffffff;
        #pragma unroll
        for (int c = 0; c < 4; ++c) {
            int base = (c * 64 + lane) * 4;
            #pragma unroll
            for (int j = 0; j < 4; ++j) {
                float e = v[c][j];
                if (e > m) { m = e; mi = base + j; }
            }
        }
        // wave reduce: max, tie-break to smallest index
        #pragma unroll
        for (int off = 1; off < 64; off <<= 1) {
            float om = __shfl_xor(m, off, 64);
            int   oi = __shfl_xor(mi, off, 64);
            if (om > m || (om == m && oi < mi)) { m = om; mi = oi; }
        }

        // sum of exp(x - max); -inf fill lanes contribute exp(-inf)=0
        float s = 0.0f;
        #pragma unroll
        for (int c = 0; c < 4; ++c) {
            #pragma unroll
            for (int j = 0; j < 4; ++j) s += __expf(v[c][j] - m);
        }
        #pragma unroll
        for (int off = 1; off < 64; off <<= 1) s += __shfl_xor(s, off, 64);

        if (lane == 0) {
            float conf = 1.0f / s;                        // exp(max-max)/Z = 1/Z
            int bin = (int)ceilf(conf * (float)N_BINS) - 1;
            bin = bin < 0 ? 0 : (bin > N_BINS - 1 ? N_BINS - 1 : bin);
            float acc = (mi == lbl) ? 1.0f : 0.0f;
            atomicAdd(&sb[bin], 1.0f);
            atomicAdd(&sb[N_BINS + bin], conf);
            atomicAdd(&sb[2 * N_BINS + bin], acc);
        }

        #pragma unroll
        for (int c = 0; c < 4; ++c) v[c] = vn[c];
    }
    __syncthreads();
    if (tid < 3 * N_BINS) atomicAdd(&gbins[tid], sb[tid]);
}

// Epilogue: 31 outputs = [ece, confs_binned[15], accs_binned[15]]
__global__ void ece_final(const float* __restrict__ gbins, float* __restrict__ out,
                          float invN) {
    __shared__ float s_ece[N_BINS];
    int i = threadIdx.x;
    if (i < N_BINS) {
        float cnt   = gbins[i];
        float sconf = gbins[N_BINS + i];
        float sacc  = gbins[2 * N_BINS + i];
        bool  ne    = cnt > 0.0f;
        float sc    = ne ? cnt : 1.0f;
        float avg_conf = sconf / sc;
        float avg_acc  = sacc / sc;
        float prop     = cnt * invN;
        s_ece[i] = ne ? fabsf(avg_conf - avg_acc) * prop : 0.0f;
        out[1 + i]          = ne ? avg_conf : ((float)i + 0.5f) / (float)N_BINS;
        out[1 + N_BINS + i] = ne ? avg_acc  : 0.0f;
    }
    __syncthreads();
    if (i == 0) {
        float e = 0.0f;
        for (int j = 0; j < N_BINS; ++j) e += s_ece[j];
        out[0] = e;
    }
}

extern "C" void kernel_launch(void* const* d_in, const int* in_sizes, int n_in,
                              void* d_out, int out_size, void* d_ws, size_t ws_size,
                              hipStream_t stream) {
    const float* logits = (const float*)d_in[0];
    const int*   labels = (const int*)d_in[1];
    int N = in_sizes[1];
    int C = in_sizes[0] / N;   // 1000

    float* gbins = (float*)d_ws;  // [3][N_BINS] accumulators
    (void)hipMemsetAsync(gbins, 0, 3 * N_BINS * sizeof(float), stream);

    const int blocks = 2048;  // 8192 waves, 32 rows/wave grid-stride
    ece_main<<<blocks, 256, 0, stream>>>(logits, labels, gbins, N, C);
    ece_final<<<1, 64, 0, stream>>>(gbins, (float*)d_out, 1.0f / (float)N);
}